// Round 3
// baseline (252.351 us; speedup 1.0000x reference)
//
#include <hip/hip_runtime.h>
#include <math.h>

#define NRES 384
#define NH   12
#define WLc 0.5773502691896258f
#define WCc 0.23570226039551587f

typedef __attribute__((ext_vector_type(8))) _Float16 half8;
typedef __attribute__((ext_vector_type(4))) float f32x4;

// workspace layout (float offsets)
#define OFF_P    0           // f32 [384][1152] proj out
#define OFF_QE   442368      // f32 [384][12][32]
#define OFF_KE   589824      // f32 [12][384][32]
#define OFF_VET  737280      // f16 [12][48][384]
#define OFF_SH   847872      // f16 [384][384]  s
#define OFF_WCT  921600      // f16 [1152][384] Wcat^T
#define OFF_BCT  1142784     // f32 [1152]
#define OFF_WOT  1143936     // f16 [384][2112] Wo^T
#define OFF_WBT  1549440     // f16 [16][128]  WLc*Wb^T (rows>=12 zero)
#define OFF_CAT  1550464     // f16 [384][2112] concat
// end 1955968 f32 = 7.8 MB

// ---------------------------------------------------------------------------
// K0: pack: s->f16; Wcat^T f16; Wo^T f16; Wb^T f16 (scaled); bcat f32
// ---------------------------------------------------------------------------
__global__ __launch_bounds__(256) void pack_kernel(
    const float* __restrict__ s,
    const float* __restrict__ Wq,  const float* __restrict__ bq,
    const float* __restrict__ Wk,  const float* __restrict__ bk,
    const float* __restrict__ Wv,  const float* __restrict__ bv,
    const float* __restrict__ Wqp, const float* __restrict__ bqp,
    const float* __restrict__ Wkp, const float* __restrict__ bkp,
    const float* __restrict__ Wvp, const float* __restrict__ bvp,
    const float* __restrict__ Wb,  const float* __restrict__ Wo,
    float* __restrict__ ws)
{
    int id = blockIdx.x * 256 + threadIdx.x;
    _Float16* sh  = (_Float16*)(ws + OFF_SH);
    _Float16* wct = (_Float16*)(ws + OFF_WCT);
    _Float16* wot = (_Float16*)(ws + OFF_WOT);
    _Float16* wbt = (_Float16*)(ws + OFF_WBT);
    float* bct = ws + OFF_BCT;

    if (id < 36864) {                      // s -> f16
        const float4 v = ((const float4*)s)[id];
        _Float16 r[4] = { (_Float16)v.x, (_Float16)v.y, (_Float16)v.z, (_Float16)v.w };
        *(uint2*)(sh + id * 4) = *(uint2*)r;
        return;
    }
    id -= 36864;
    if (id < 55296) {                      // Wcat^T
        int n = id / 48, k8 = (id % 48) * 8;
        const float* W; int dout, col;
        if      (n < 192) { W = Wq;  dout = 192; col = n; }
        else if (n < 384) { W = Wk;  dout = 192; col = n - 192; }
        else if (n < 576) { W = Wv;  dout = 192; col = n - 384; }
        else if (n < 720) { W = Wqp; dout = 144; col = n - 576; }
        else if (n < 864) { W = Wkp; dout = 144; col = n - 720; }
        else              { W = Wvp; dout = 288; col = n - 864; }
        half8 r;
        #pragma unroll
        for (int j = 0; j < 8; j++) r[j] = (_Float16)W[(size_t)(k8 + j) * dout + col];
        *(half8*)(wct + (size_t)n * 384 + k8) = r;
        return;
    }
    id -= 55296;
    if (id < 101376) {                     // Wo^T
        int n = id / 264, k8 = (id % 264) * 8;
        half8 r;
        #pragma unroll
        for (int j = 0; j < 8; j++) r[j] = (_Float16)Wo[(size_t)(k8 + j) * 384 + n];
        *(half8*)(wot + (size_t)n * 2112 + k8) = r;
        return;
    }
    id -= 101376;
    if (id < 2048) {                       // Wb^T scaled by WLc, rows>=12 zero
        int h = id >> 7, c = id & 127;
        wbt[h * 128 + c] = (h < 12) ? (_Float16)(WLc * Wb[c * 12 + h]) : (_Float16)0.f;
        return;
    }
    id -= 2048;
    if (id < 1152) {
        int n = id; float b;
        if      (n < 192) b = bq[n];
        else if (n < 384) b = bk[n - 192];
        else if (n < 576) b = bv[n - 384];
        else if (n < 720) b = bqp[n - 576];
        else if (n < 864) b = bkp[n - 720];
        else              b = bvp[n - 864];
        bct[n] = b;
    }
}

// ---------------------------------------------------------------------------
// K1: proj MFMA (f16): P(384x1152) = s @ Wcat + bcat
// ---------------------------------------------------------------------------
__global__ __launch_bounds__(256) void proj_mfma(float* __restrict__ ws)
{
    const _Float16* sh  = (const _Float16*)(ws + OFF_SH);
    const _Float16* wct = (const _Float16*)(ws + OFF_WCT);
    const float* bct = ws + OFF_BCT;
    float* P = ws + OFF_P;

    int t = threadIdx.x, w = t >> 6, lane = t & 63;
    int m = lane & 15, q = lane >> 4;
    int n0 = blockIdx.x * 64, m0 = blockIdx.y * 64 + w * 16;

    f32x4 acc[4] = {0};
    const _Float16* arow = sh + (size_t)(m0 + m) * 384;
    #pragma unroll 4
    for (int s = 0; s < 12; s++) {
        int k = s * 32 + q * 8;
        half8 a = *(const half8*)(arow + k);
        #pragma unroll
        for (int nt = 0; nt < 4; nt++) {
            half8 b = *(const half8*)(wct + (size_t)(n0 + nt * 16 + m) * 384 + k);
            acc[nt] = __builtin_amdgcn_mfma_f32_16x16x32_f16(a, b, acc[nt], 0, 0, 0);
        }
    }
    #pragma unroll
    for (int nt = 0; nt < 4; nt++) {
        int col = n0 + nt * 16 + m;
        float bias = bct[col];
        #pragma unroll
        for (int r = 0; r < 4; r++)
            P[(size_t)(m0 + q * 4 + r) * 1152 + col] = acc[nt][r] + bias;
    }
}

// ---------------------------------------------------------------------------
// K2: prep — per-i block. Qe[i][h][32] f32, Ke[h][i][32] f32, Ve_t f16
// ---------------------------------------------------------------------------
__global__ __launch_bounds__(192) void prep_kernel(
    const float* __restrict__ T, const float* __restrict__ hw,
    float* __restrict__ ws)
{
    int i = blockIdx.x, t = threadIdx.x;
    const float* pr = ws + OFF_P + (size_t)i * 1152;
    float* Qe = ws + OFF_QE;
    float* Ke = ws + OFF_KE;
    _Float16* vet = (_Float16*)(ws + OFF_VET);

    __shared__ float sT[16], sG[12];
    __shared__ float sTQ[12][4][3], sTK[12][4][3];
    if (t < 16) sT[t] = T[i * 16 + t];
    if (t < 12) { float x = hw[t]; sG[t] = (x > 20.f) ? x : log1pf(__expf(x)); }
    __syncthreads();
    float R00=sT[0],R01=sT[1],R02=sT[2],t0=sT[3];
    float R10=sT[4],R11=sT[5],R12=sT[6],t1=sT[7];
    float R20=sT[8],R21=sT[9],R22=sT[10],t2=sT[11];

    if (t < 48) {            // q-points
        int h = t >> 2, p = t & 3;
        float a0 = pr[576 + 0*48 + h*4 + p], a1 = pr[576 + 1*48 + h*4 + p], a2 = pr[576 + 2*48 + h*4 + p];
        sTQ[h][p][0] = R00*a0 + R01*a1 + R02*a2 + t0;
        sTQ[h][p][1] = R10*a0 + R11*a1 + R12*a2 + t1;
        sTQ[h][p][2] = R20*a0 + R21*a1 + R22*a2 + t2;
    } else if (t < 96) {     // k-points
        int tt = t - 48, h = tt >> 2, p = tt & 3;
        float a0 = pr[720 + 0*48 + h*4 + p], a1 = pr[720 + 1*48 + h*4 + p], a2 = pr[720 + 2*48 + h*4 + p];
        sTK[h][p][0] = R00*a0 + R01*a1 + R02*a2 + t0;
        sTK[h][p][1] = R10*a0 + R11*a1 + R12*a2 + t1;
        sTK[h][p][2] = R20*a0 + R21*a1 + R22*a2 + t2;
    } else {                 // v-points -> Ve_t directly
        int tt = t - 96, h = tt >> 3, p = tt & 7;
        float a0 = pr[864 + 0*96 + h*8 + p], a1 = pr[864 + 1*96 + h*8 + p], a2 = pr[864 + 2*96 + h*8 + p];
        vet[(size_t)(h*48 + 16 + p*3 + 0) * 384 + i] = (_Float16)(R00*a0 + R01*a1 + R02*a2 + t0);
        vet[(size_t)(h*48 + 16 + p*3 + 1) * 384 + i] = (_Float16)(R10*a0 + R11*a1 + R12*a2 + t1);
        vet[(size_t)(h*48 + 16 + p*3 + 2) * 384 + i] = (_Float16)(R20*a0 + R21*a1 + R22*a2 + t2);
    }
    {   // v 16-chan copy + zero pad
        int h = t >> 4, c = t & 15;
        vet[(size_t)(h*48 + c) * 384 + i] = (_Float16)pr[384 + h*16 + c];
        if (t < 96) vet[(size_t)((t>>3)*48 + 40 + (t&7)) * 384 + i] = (_Float16)0.f;
    }
    {   // q/k 16-chan
        int h = t >> 4, c = t & 15;
        Qe[(size_t)i*384 + h*32 + c] = WLc * 0.25f * pr[h*16 + c];
        Ke[((size_t)h*384 + i)*32 + c] = pr[192 + h*16 + c];
    }
    __syncthreads();
    if (t < 144) {           // point channels
        int h = t / 12, d = t % 12, p = d / 3, r = d % 3;
        float gw = WLc * sG[h] * WCc;
        Qe[(size_t)i*384 + h*32 + 16 + d] = gw * sTQ[h][p][r];
        Ke[((size_t)h*384 + i)*32 + 16 + d] = sTK[h][p][r];
    }
    if (t < 12) {            // tails
        int h = t;
        float sqq = 0.f, sqk = 0.f;
        #pragma unroll
        for (int p = 0; p < 4; p++)
            #pragma unroll
            for (int r = 0; r < 3; r++) { sqq += sTQ[h][p][r]*sTQ[h][p][r]; sqk += sTK[h][p][r]*sTK[h][p][r]; }
        float gw = WLc * sG[h] * WCc;
        Qe[(size_t)i*384 + h*32 + 28] = -0.5f * gw;
        Qe[(size_t)i*384 + h*32 + 29] = -0.5f * gw * sqq;
        Qe[(size_t)i*384 + h*32 + 30] = 0.f;
        Qe[(size_t)i*384 + h*32 + 31] = 0.f;
        Ke[((size_t)h*384 + i)*32 + 28] = sqk;
        Ke[((size_t)h*384 + i)*32 + 29] = 1.f;
        Ke[((size_t)h*384 + i)*32 + 30] = 0.f;
        Ke[((size_t)h*384 + i)*32 + 31] = 0.f;
    }
}

// ---------------------------------------------------------------------------
// K3: flash attention per residue i. One z pass: bias MFMA + fp32 logits +
// online softmax + pairwise MFMA + o40 VALU. Writes full concat row (f16).
// ---------------------------------------------------------------------------
__global__ __launch_bounds__(256) void flash_kernel(
    const float* __restrict__ z, const float* __restrict__ T,
    const float* __restrict__ bb, float* __restrict__ ws)
{
    int i = blockIdx.x, t = threadIdx.x, w = t >> 6, lane = t & 63;
    int m16 = lane & 15, q = lane >> 4;

    __shared__ _Float16 zc[64 * 136];     // z chunk [j][c], pad 136
    __shared__ _Float16 attc[16 * 72];    // att chunk [h][j], pad 72
    __shared__ _Float16 wbl[16 * 136];    // WLc*Wb^T
    __shared__ float bias_ch[64 * 17];    // [j][h]
    __shared__ float sQe[384];
    __shared__ float sT[16], sBB[12], sM[12], sL[12], sAl[16], sInv[12];
    __shared__ float sO[480];

    const float* Qe = ws + OFF_QE;
    const float* Ke = ws + OFF_KE;
    const _Float16* vet = (const _Float16*)(ws + OFF_VET);
    const _Float16* wbt = (const _Float16*)(ws + OFF_WBT);
    _Float16* crow = (_Float16*)(ws + OFF_CAT) + (size_t)i * 2112;

    if (t < 16) sT[t] = T[i * 16 + t];
    if (t < 12) { sBB[t] = WLc * bb[t]; sM[t] = -1e30f; sL[t] = 0.f; }
    if (t >= 12 && t < 16) sAl[t] = 0.f;
    for (int e = t; e < 384; e += 256) sQe[e] = Qe[(size_t)i * 384 + e];
    {   // wbl stage
        int row = t >> 4, c8 = (t & 15) * 8;
        *(half8*)(wbl + row * 136 + c8) = *(const half8*)(wbt + row * 128 + c8);
    }
    for (int e = t; e < 4 * 72; e += 256) attc[12 * 72 + e] = (_Float16)0.f;
    __syncthreads();

    f32x4 apw[2] = {0};                  // pairwise acc: c = w*32+sub*16+m16, h = q*4+r
    float ao0 = 0.f, ao1 = 0.f;          // o40 acc
    int h40 = t / 20, c40 = (t % 20) * 2;

    for (int ch = 0; ch < 6; ch++) {
        int j0 = ch * 64;
        __syncthreads();
        {   // load z chunk -> f16 LDS
            int jr = t >> 2, cg = (t & 3) * 32;
            const float* zp = z + ((size_t)i * 384 + j0 + jr) * 128 + cg;
            #pragma unroll
            for (int u = 0; u < 4; u++) {
                float4 v0 = ((const float4*)zp)[u * 2];
                float4 v1 = ((const float4*)zp)[u * 2 + 1];
                half8 r;
                r[0]=(_Float16)v0.x; r[1]=(_Float16)v0.y; r[2]=(_Float16)v0.z; r[3]=(_Float16)v0.w;
                r[4]=(_Float16)v1.x; r[5]=(_Float16)v1.y; r[6]=(_Float16)v1.z; r[7]=(_Float16)v1.w;
                *(half8*)(zc + jr * 136 + cg + u * 8) = r;
            }
        }
        __syncthreads();
        {   // bias MFMA: wave w -> rows j = w*16+m16
            f32x4 bacc = {0};
            #pragma unroll
            for (int s = 0; s < 4; s++) {
                half8 a = *(const half8*)(zc + (w * 16 + m16) * 136 + s * 32 + q * 8);
                half8 b = *(const half8*)(wbl + m16 * 136 + s * 32 + q * 8);
                bacc = __builtin_amdgcn_mfma_f32_16x16x32_f16(a, b, bacc, 0, 0, 0);
            }
            #pragma unroll
            for (int r = 0; r < 4; r++)
                bias_ch[(w * 16 + q * 4 + r) * 17 + m16] = bacc[r];
        }
        __syncthreads();
        {   // logits + online softmax: wave w owns h = 3w..3w+2, lane = local j
            #pragma unroll
            for (int u = 0; u < 3; u++) {
                int h = w * 3 + u;
                float lg = bias_ch[lane * 17 + h] + sBB[h];
                const float4* k4 = (const float4*)(Ke + ((size_t)h * 384 + j0 + lane) * 32);
                #pragma unroll
                for (int uu = 0; uu < 8; uu++) {
                    float4 kv = k4[uu];
                    lg += sQe[h*32 + uu*4 + 0] * kv.x + sQe[h*32 + uu*4 + 1] * kv.y
                        + sQe[h*32 + uu*4 + 2] * kv.z + sQe[h*32 + uu*4 + 3] * kv.w;
                }
                float mx = lg;
                #pragma unroll
                for (int off = 1; off < 64; off <<= 1) mx = fmaxf(mx, __shfl_xor(mx, off));
                float mold = sM[h];
                float mnew = fmaxf(mold, mx);
                float e = __expf(lg - mnew);
                float ssum = e;
                #pragma unroll
                for (int off = 1; off < 64; off <<= 1) ssum += __shfl_xor(ssum, off);
                float alpha = __expf(mold - mnew);
                if (lane == 0) { sM[h] = mnew; sL[h] = sL[h] * alpha + ssum; sAl[h] = alpha; }
                attc[h * 72 + lane] = (_Float16)e;
            }
        }
        __syncthreads();
        {   // pairwise MFMA: wave w covers c in [w*32, w*32+32)
            float al[4];
            #pragma unroll
            for (int r = 0; r < 4; r++) al[r] = sAl[q * 4 + r];
            #pragma unroll
            for (int sub = 0; sub < 2; sub++)
                #pragma unroll
                for (int r = 0; r < 4; r++) apw[sub][r] *= al[r];
            #pragma unroll
            for (int ks = 0; ks < 2; ks++) {
                half8 a = *(const half8*)(attc + m16 * 72 + ks * 32 + q * 8);
                #pragma unroll
                for (int sub = 0; sub < 2; sub++) {
                    int c = w * 32 + sub * 16 + m16;
                    half8 b;
                    #pragma unroll
                    for (int jj = 0; jj < 8; jj++) b[jj] = zc[(ks * 32 + q * 8 + jj) * 136 + c];
                    apw[sub] = __builtin_amdgcn_mfma_f32_16x16x32_f16(a, b, apw[sub], 0, 0, 0);
                }
            }
        }
        if (t < 240) {   // o40 VALU
            float al = sAl[h40];
            float a0 = ao0 * al, a1 = ao1 * al;
            const _Float16* vp0 = vet + ((size_t)(h40 * 48 + c40)) * 384 + j0;
            const _Float16* vp1 = vp0 + 384;
            #pragma unroll
            for (int hf = 0; hf < 2; hf++) {
                half8 v0[4], v1[4];
                #pragma unroll
                for (int u = 0; u < 4; u++) {
                    v0[u] = *(const half8*)(vp0 + hf * 32 + u * 8);
                    v1[u] = *(const half8*)(vp1 + hf * 32 + u * 8);
                }
                #pragma unroll
                for (int u = 0; u < 4; u++)
                    #pragma unroll
                    for (int jj = 0; jj < 8; jj++) {
                        float av = (float)attc[h40 * 72 + hf * 32 + u * 8 + jj];
                        a0 += av * (float)v0[u][jj];
                        a1 += av * (float)v1[u][jj];
                    }
            }
            ao0 = a0; ao1 = a1;
        }
    }
    __syncthreads();
    if (t < 12) sInv[t] = 1.0f / sL[t];
    __syncthreads();
    {   // pairwise write -> concat cols 576..2111
        #pragma unroll
        for (int sub = 0; sub < 2; sub++)
            #pragma unroll
            for (int r = 0; r < 4; r++) {
                int h = q * 4 + r;
                if (h < 12)
                    crow[576 + h * 128 + w * 32 + sub * 16 + m16] = (_Float16)(apw[sub][r] * sInv[h]);
            }
    }
    if (t < 240) {
        sO[h40 * 40 + c40]     = ao0 * sInv[h40];
        sO[h40 * 40 + c40 + 1] = ao1 * sInv[h40];
    }
    __syncthreads();
    if (t < 192) crow[t] = (_Float16)sO[(t >> 4) * 40 + (t & 15)];
    if (t < 96) {
        int h = t >> 3, p = t & 7;
        const float* o = sO + h * 40 + 16 + p * 3;
        float x0 = o[0] - sT[3];
        float x1 = o[1] - sT[7];
        float x2 = o[2] - sT[11];
        float r0 = sT[0]*x0 + sT[4]*x1 + sT[8]*x2;
        float r1 = sT[1]*x0 + sT[5]*x1 + sT[9]*x2;
        float r2 = sT[2]*x0 + sT[6]*x1 + sT[10]*x2;
        crow[192 + 0*96 + h*8 + p] = (_Float16)r0;
        crow[192 + 1*96 + h*8 + p] = (_Float16)r1;
        crow[192 + 2*96 + h*8 + p] = (_Float16)r2;
        crow[480 + h*8 + p] = (_Float16)sqrtf(r0*r0 + r1*r1 + r2*r2);
    }
}

// ---------------------------------------------------------------------------
// K4: out init with bo
// ---------------------------------------------------------------------------
__global__ __launch_bounds__(256) void out_init(const float* __restrict__ bo, float* __restrict__ out)
{
    int idx = blockIdx.x * 256 + threadIdx.x;
    if (idx < 384 * 384) out[idx] = bo[idx % 384];
}

// ---------------------------------------------------------------------------
// K5: out GEMM MFMA (f16): concat(384x2112) @ Wo, k-split 3, atomicAdd
// ---------------------------------------------------------------------------
__global__ __launch_bounds__(256) void outgemm_mfma(float* __restrict__ ws, float* __restrict__ out)
{
    const _Float16* catb = (const _Float16*)(ws + OFF_CAT);
    const _Float16* wot  = (const _Float16*)(ws + OFF_WOT);

    int t = threadIdx.x, w = t >> 6, lane = t & 63;
    int m = lane & 15, q = lane >> 4;
    int n0 = blockIdx.x * 64, m0 = blockIdx.y * 64 + w * 16;
    int kbase = blockIdx.z * 704;

    f32x4 acc[4] = {0};
    const _Float16* arow = catb + (size_t)(m0 + m) * 2112;
    #pragma unroll 2
    for (int s = 0; s < 22; s++) {
        int k = kbase + s * 32 + q * 8;
        half8 a = *(const half8*)(arow + k);
        #pragma unroll
        for (int nt = 0; nt < 4; nt++) {
            half8 b = *(const half8*)(wot + (size_t)(n0 + nt * 16 + m) * 2112 + k);
            acc[nt] = __builtin_amdgcn_mfma_f32_16x16x32_f16(a, b, acc[nt], 0, 0, 0);
        }
    }
    #pragma unroll
    for (int nt = 0; nt < 4; nt++) {
        int col = n0 + nt * 16 + m;
        #pragma unroll
        for (int r = 0; r < 4; r++)
            atomicAdd(&out[(size_t)(m0 + q * 4 + r) * 384 + col], acc[nt][r]);
    }
}

extern "C" void kernel_launch(void* const* d_in, const int* in_sizes, int n_in,
                              void* d_out, int out_size, void* d_ws, size_t ws_size,
                              hipStream_t stream)
{
    const float* s   = (const float*)d_in[0];
    const float* z   = (const float*)d_in[1];
    const float* T   = (const float*)d_in[2];
    const float* Wq  = (const float*)d_in[3];
    const float* bq  = (const float*)d_in[4];
    const float* Wk  = (const float*)d_in[5];
    const float* bk  = (const float*)d_in[6];
    const float* Wv  = (const float*)d_in[7];
    const float* bv  = (const float*)d_in[8];
    const float* Wqp = (const float*)d_in[9];
    const float* bqp = (const float*)d_in[10];
    const float* Wkp = (const float*)d_in[11];
    const float* bkp = (const float*)d_in[12];
    const float* Wvp = (const float*)d_in[13];
    const float* bvp = (const float*)d_in[14];
    const float* Wb  = (const float*)d_in[15];
    const float* bb  = (const float*)d_in[16];
    const float* Wo  = (const float*)d_in[17];
    const float* bo  = (const float*)d_in[18];
    const float* hw  = (const float*)d_in[19];
    float* ws  = (float*)d_ws;
    float* out = (float*)d_out;

    pack_kernel<<<769, 256, 0, stream>>>(s, Wq, bq, Wk, bk, Wv, bv,
                                         Wqp, bqp, Wkp, bkp, Wvp, bvp, Wb, Wo, ws);
    proj_mfma<<<dim3(18, 6), 256, 0, stream>>>(ws);
    prep_kernel<<<384, 192, 0, stream>>>(T, hw, ws);
    flash_kernel<<<384, 256, 0, stream>>>(z, T, bb, ws);
    out_init<<<576, 256, 0, stream>>>(bo, out);
    outgemm_mfma<<<dim3(6, 6, 3), 256, 0, stream>>>(ws, out);
}